// Round 1
// baseline (2562.923 us; speedup 1.0000x reference)
//
#include <hip/hip_runtime.h>

#define NN 100000
#define NC 16
#define NE 3200000
#define NLAYERS 4
#define ALPHA_C 0.5f

// 4 threads per edge; each thread handles a float4 slice (4 classes) of the
// 16-class message. msg = h[src] * W[src] * ew ; atomic-add into agg[dst].
__global__ void lp_scatter(const float* __restrict__ h,
                           const float* __restrict__ W,
                           const float* __restrict__ ew,
                           const int* __restrict__ src,
                           const int* __restrict__ dst,
                           float* __restrict__ agg)
{
    long long t = (long long)blockIdx.x * blockDim.x + threadIdx.x;
    int e = (int)(t >> 2);
    int q = (int)(t & 3);
    if (e >= NE) return;
    int s = src[e];
    int d = dst[e];
    float w = ew[e] * W[s];
    const float4 hv = *reinterpret_cast<const float4*>(h + (size_t)s * NC + q * 4);
    float* out = agg + (size_t)d * NC + q * 4;
    unsafeAtomicAdd(out + 0, hv.x * w);
    unsafeAtomicAdd(out + 1, hv.y * w);
    unsafeAtomicAdd(out + 2, hv.z * w);
    unsafeAtomicAdd(out + 3, hv.w * w);
}

// per-node epilogue: v = ALPHA*h + (1-ALPHA)*deg^2*agg ; v /= rowsum(v)
__global__ void lp_node(const float* __restrict__ h,
                        const float* __restrict__ agg,
                        const float* __restrict__ degree,
                        float* __restrict__ hout)
{
    int n = blockIdx.x * blockDim.x + threadIdx.x;
    if (n >= NN) return;
    float deg = degree[n];
    float d2 = deg * deg;
    const float4* hp = reinterpret_cast<const float4*>(h + (size_t)n * NC);
    const float4* ap = reinterpret_cast<const float4*>(agg + (size_t)n * NC);
    float4 v[4];
    float sum = 0.f;
#pragma unroll
    for (int i = 0; i < 4; ++i) {
        float4 hv = hp[i];
        float4 av = ap[i];
        v[i].x = ALPHA_C * hv.x + (1.f - ALPHA_C) * d2 * av.x;
        v[i].y = ALPHA_C * hv.y + (1.f - ALPHA_C) * d2 * av.y;
        v[i].z = ALPHA_C * hv.z + (1.f - ALPHA_C) * d2 * av.z;
        v[i].w = ALPHA_C * hv.w + (1.f - ALPHA_C) * d2 * av.w;
        sum += v[i].x + v[i].y + v[i].z + v[i].w;
    }
    float inv = 1.f / sum;
    float4* op = reinterpret_cast<float4*>(hout + (size_t)n * NC);
#pragma unroll
    for (int i = 0; i < 4; ++i) {
        v[i].x *= inv; v[i].y *= inv; v[i].z *= inv; v[i].w *= inv;
        op[i] = v[i];
    }
}

extern "C" void kernel_launch(void* const* d_in, const int* in_sizes, int n_in,
                              void* d_out, int out_size, void* d_ws, size_t ws_size,
                              hipStream_t stream)
{
    const float* x      = (const float*)d_in[0];
    const float* W      = (const float*)d_in[1];
    const float* ew     = (const float*)d_in[2];
    const float* degree = (const float*)d_in[3];
    const int*   eidx   = (const int*)d_in[4];
    const int* src = eidx;
    const int* dst = eidx + NE;
    float* out  = (float*)d_out;

    float* bufA = (float*)d_ws;
    float* agg  = bufA + (size_t)NN * NC;

    const size_t agg_bytes = (size_t)NN * NC * sizeof(float);

    const int scat_threads = NE * 4;
    const int scat_blocks  = (scat_threads + 255) / 256;
    const int node_blocks  = (NN + 255) / 256;

    const float* hin = x;
    float* houts[NLAYERS] = {bufA, out, bufA, out};

    for (int l = 0; l < NLAYERS; ++l) {
        hipMemsetAsync(agg, 0, agg_bytes, stream);
        lp_scatter<<<scat_blocks, 256, 0, stream>>>(hin, W, ew, src, dst, agg);
        lp_node<<<node_blocks, 256, 0, stream>>>(hin, agg, degree, houts[l]);
        hin = houts[l];
    }
}

// Round 2
// 522.835 us; speedup vs baseline: 4.9020x; 4.9020x over previous
//
#include <hip/hip_runtime.h>

#define NN 100000
#define NC 16
#define NE 3200000
#define NLAYERS 4
#define ALPHA_C 0.5f

// ===================== build phase (once per launch) =====================

__global__ void hist_kernel(const int* __restrict__ dst, int* __restrict__ counts) {
    int e = blockIdx.x * blockDim.x + threadIdx.x;
    if (e < NE) atomicAdd(&counts[dst[e]], 1);
}

// Exclusive scan, 1024 elements per block (256 threads x 4 elems).
__global__ void scanA(int* __restrict__ data, int* __restrict__ blockSums, int n) {
    __shared__ int lds[256];
    int base = blockIdx.x * 1024 + threadIdx.x * 4;
    int v[4] = {0, 0, 0, 0};
#pragma unroll
    for (int i = 0; i < 4; ++i) { int idx = base + i; if (idx < n) v[i] = data[idx]; }
    int tsum = v[0] + v[1] + v[2] + v[3];
    lds[threadIdx.x] = tsum;
    __syncthreads();
    // Hillis-Steele inclusive scan over 256 thread sums
    for (int off = 1; off < 256; off <<= 1) {
        int t = (threadIdx.x >= off) ? lds[threadIdx.x - off] : 0;
        __syncthreads();
        lds[threadIdx.x] += t;
        __syncthreads();
    }
    if (threadIdx.x == 255) blockSums[blockIdx.x] = lds[255];
    int run = lds[threadIdx.x] - tsum;  // exclusive prefix for this thread
#pragma unroll
    for (int i = 0; i < 4; ++i) {
        int idx = base + i;
        if (idx < n) { int old = v[i]; data[idx] = run; run += old; }
    }
}

__global__ void scanB(int* __restrict__ blockSums, int nb) {
    __shared__ int lds[128];
    int t = threadIdx.x;
    if (t < nb) lds[t] = blockSums[t];
    __syncthreads();
    if (t == 0) {
        int run = 0;
        for (int i = 0; i < nb; ++i) { int x = lds[i]; lds[i] = run; run += x; }
    }
    __syncthreads();
    if (t < nb) blockSums[t] = lds[t];
}

__global__ void scanC(int* __restrict__ data, const int* __restrict__ blockSums, int n) {
    int idx = blockIdx.x * blockDim.x + threadIdx.x;
    if (idx < n) data[idx] += blockSums[idx >> 10];
    if (idx == 0) data[n] = NE;  // offsets[NN] = total edge count
}

// Place each edge into its dst-segment; fold W[src]*ew into the stored weight.
__global__ void scatter_sort(const int* __restrict__ src, const int* __restrict__ dst,
                             const float* __restrict__ ew, const float* __restrict__ W,
                             const int* __restrict__ offsets, int* __restrict__ cursor,
                             int2* __restrict__ sorted) {
    int e = blockIdx.x * blockDim.x + threadIdx.x;
    if (e >= NE) return;
    int d = dst[e];
    int s = src[e];
    int pos = offsets[d] + atomicAdd(&cursor[d], 1);
    float w = ew[e] * W[s];
    sorted[pos] = make_int2(s, __float_as_int(w));
}

// ===================== per-layer gather (no atomics) =====================
// 4 lanes per node; lane q owns classes [4q, 4q+4). Fused epilogue:
// v = a*h + (1-a)*deg^2*agg ; v /= rowsum(v) via 2x shfl_xor.
__global__ void gather_kernel(const float* __restrict__ h,
                              const int2* __restrict__ sorted,
                              const int* __restrict__ offsets,
                              const float* __restrict__ degree,
                              float* __restrict__ hout) {
    int t = blockIdx.x * blockDim.x + threadIdx.x;
    int g = t >> 2;
    int q = t & 3;
    if (g >= NN) return;
    int beg = offsets[g];
    int end = offsets[g + 1];
    float4 acc = make_float4(0.f, 0.f, 0.f, 0.f);
    for (int i = beg; i < end; ++i) {
        int2 rec = sorted[i];
        float w = __int_as_float(rec.y);
        const float4 hv = *reinterpret_cast<const float4*>(h + (size_t)rec.x * NC + q * 4);
        acc.x += hv.x * w;
        acc.y += hv.y * w;
        acc.z += hv.z * w;
        acc.w += hv.w * w;
    }
    float deg = degree[g];
    float d2 = deg * deg;
    const float4 hs = *reinterpret_cast<const float4*>(h + (size_t)g * NC + q * 4);
    float4 v;
    v.x = ALPHA_C * hs.x + (1.f - ALPHA_C) * d2 * acc.x;
    v.y = ALPHA_C * hs.y + (1.f - ALPHA_C) * d2 * acc.y;
    v.z = ALPHA_C * hs.z + (1.f - ALPHA_C) * d2 * acc.z;
    v.w = ALPHA_C * hs.w + (1.f - ALPHA_C) * d2 * acc.w;
    float s4 = v.x + v.y + v.z + v.w;
    s4 += __shfl_xor(s4, 1);
    s4 += __shfl_xor(s4, 2);
    float inv = 1.f / s4;
    float4* op = reinterpret_cast<float4*>(hout + (size_t)g * NC + q * 4);
    v.x *= inv; v.y *= inv; v.z *= inv; v.w *= inv;
    *op = v;
}

// ===================== fallback (atomic scatter, round-1 path) =====================

__global__ void lp_scatter(const float* __restrict__ h,
                           const float* __restrict__ W,
                           const float* __restrict__ ew,
                           const int* __restrict__ src,
                           const int* __restrict__ dst,
                           float* __restrict__ agg)
{
    long long t = (long long)blockIdx.x * blockDim.x + threadIdx.x;
    int e = (int)(t >> 2);
    int q = (int)(t & 3);
    if (e >= NE) return;
    int s = src[e];
    int d = dst[e];
    float w = ew[e] * W[s];
    const float4 hv = *reinterpret_cast<const float4*>(h + (size_t)s * NC + q * 4);
    float* out = agg + (size_t)d * NC + q * 4;
    unsafeAtomicAdd(out + 0, hv.x * w);
    unsafeAtomicAdd(out + 1, hv.y * w);
    unsafeAtomicAdd(out + 2, hv.z * w);
    unsafeAtomicAdd(out + 3, hv.w * w);
}

__global__ void lp_node(const float* __restrict__ h,
                        const float* __restrict__ agg,
                        const float* __restrict__ degree,
                        float* __restrict__ hout)
{
    int n = blockIdx.x * blockDim.x + threadIdx.x;
    if (n >= NN) return;
    float deg = degree[n];
    float d2 = deg * deg;
    const float4* hp = reinterpret_cast<const float4*>(h + (size_t)n * NC);
    const float4* ap = reinterpret_cast<const float4*>(agg + (size_t)n * NC);
    float4 v[4];
    float sum = 0.f;
#pragma unroll
    for (int i = 0; i < 4; ++i) {
        float4 hv = hp[i];
        float4 av = ap[i];
        v[i].x = ALPHA_C * hv.x + (1.f - ALPHA_C) * d2 * av.x;
        v[i].y = ALPHA_C * hv.y + (1.f - ALPHA_C) * d2 * av.y;
        v[i].z = ALPHA_C * hv.z + (1.f - ALPHA_C) * d2 * av.z;
        v[i].w = ALPHA_C * hv.w + (1.f - ALPHA_C) * d2 * av.w;
        sum += v[i].x + v[i].y + v[i].z + v[i].w;
    }
    float inv = 1.f / sum;
    float4* op = reinterpret_cast<float4*>(hout + (size_t)n * NC);
#pragma unroll
    for (int i = 0; i < 4; ++i) {
        v[i].x *= inv; v[i].y *= inv; v[i].z *= inv; v[i].w *= inv;
        op[i] = v[i];
    }
}

// ===================== launch =====================

extern "C" void kernel_launch(void* const* d_in, const int* in_sizes, int n_in,
                              void* d_out, int out_size, void* d_ws, size_t ws_size,
                              hipStream_t stream)
{
    const float* x      = (const float*)d_in[0];
    const float* W      = (const float*)d_in[1];
    const float* ew     = (const float*)d_in[2];
    const float* degree = (const float*)d_in[3];
    const int*   eidx   = (const int*)d_in[4];
    const int* src = eidx;
    const int* dst = eidx + NE;
    float* out = (float*)d_out;

    const int node_threads = NN * 4;
    const int node_blocks4 = (node_threads + 255) / 256;
    const int edge_blocks  = (NE + 255) / 256;

    // ws layout: [sorted int2 NE][bufA NN*NC f32][offsets NN+1][cursor NN][blockSums 128]
    const size_t sorted_elems = (size_t)NE;
    const size_t bufA_elems   = (size_t)NN * NC;
    size_t need = sorted_elems * 8 + bufA_elems * 4 + (size_t)(NN + 1) * 4 + (size_t)NN * 4 + 128 * 4 + 64;

    if (ws_size >= need) {
        int2*  sorted    = (int2*)d_ws;
        float* bufA      = (float*)(sorted + sorted_elems);
        int*   offsets   = (int*)(bufA + bufA_elems);
        int*   cursor    = offsets + (NN + 1);
        int*   blockSums = cursor + NN;

        // zero offsets (counts) + cursor in one shot (contiguous)
        hipMemsetAsync(offsets, 0, (size_t)(2 * NN + 1) * sizeof(int), stream);

        hist_kernel<<<edge_blocks, 256, 0, stream>>>(dst, offsets);
        const int NB = (NN + 1023) / 1024;  // 98
        scanA<<<NB, 256, 0, stream>>>(offsets, blockSums, NN);
        scanB<<<1, 128, 0, stream>>>(blockSums, NB);
        scanC<<<(NN + 255) / 256, 256, 0, stream>>>(offsets, blockSums, NN);
        scatter_sort<<<edge_blocks, 256, 0, stream>>>(src, dst, ew, W, offsets, cursor, sorted);

        const float* hin = x;
        float* houts[NLAYERS] = {bufA, out, bufA, out};
        for (int l = 0; l < NLAYERS; ++l) {
            gather_kernel<<<node_blocks4, 256, 0, stream>>>(hin, sorted, offsets, degree, houts[l]);
            hin = houts[l];
        }
    } else {
        // fallback: atomic scatter path
        float* bufA = (float*)d_ws;
        float* agg  = bufA + bufA_elems;
        const size_t agg_bytes = bufA_elems * sizeof(float);
        const int scat_blocks = (NE * 4 + 255) / 256;
        const int node_blocks = (NN + 255) / 256;
        const float* hin = x;
        float* houts[NLAYERS] = {bufA, out, bufA, out};
        for (int l = 0; l < NLAYERS; ++l) {
            hipMemsetAsync(agg, 0, agg_bytes, stream);
            lp_scatter<<<scat_blocks, 256, 0, stream>>>(hin, W, ew, src, dst, agg);
            lp_node<<<node_blocks, 256, 0, stream>>>(hin, agg, degree, houts[l]);
            hin = houts[l];
        }
    }
}

// Round 3
// 490.772 us; speedup vs baseline: 5.2222x; 1.0653x over previous
//
#include <hip/hip_runtime.h>

#define NN 100000
#define NC 16
#define NE 3200000
#define NLAYERS 4
#define ALPHA_C 0.5f
#define NPART 8
#define CHUNK 400000        // NE / NPART
#define SCAT_J 160          // sub-blocks per partition
#define SCAT_EDGES 2500     // CHUNK / SCAT_J

// ============ build phase ============

// Fused histogram + rank: rank[e] = #prior edges with same (partition, dst).
__global__ void hist_rank(const int* __restrict__ dst, int* __restrict__ counts,
                          unsigned short* __restrict__ rank) {
    int e = blockIdx.x * blockDim.x + threadIdx.x;
    if (e >= NE) return;
    int d = __builtin_nontemporal_load(dst + e);
    int p = e / CHUNK;
    int r = atomicAdd(&counts[p * NN + d], 1);
    __builtin_nontemporal_store((unsigned short)r, rank + e);
}

// Exclusive scan, 1024 elements per block (256 threads x 4 elems).
__global__ void scanA(int* __restrict__ data, int* __restrict__ blockSums, int n) {
    __shared__ int lds[256];
    int base = blockIdx.x * 1024 + threadIdx.x * 4;
    int v[4] = {0, 0, 0, 0};
#pragma unroll
    for (int i = 0; i < 4; ++i) { int idx = base + i; if (idx < n) v[i] = data[idx]; }
    int tsum = v[0] + v[1] + v[2] + v[3];
    lds[threadIdx.x] = tsum;
    __syncthreads();
    for (int off = 1; off < 256; off <<= 1) {
        int t = (threadIdx.x >= off) ? lds[threadIdx.x - off] : 0;
        __syncthreads();
        lds[threadIdx.x] += t;
        __syncthreads();
    }
    if (threadIdx.x == 255) blockSums[blockIdx.x] = lds[255];
    int run = lds[threadIdx.x] - tsum;
#pragma unroll
    for (int i = 0; i < 4; ++i) {
        int idx = base + i;
        if (idx < n) { int old = v[i]; data[idx] = run; run += old; }
    }
}

// Exclusive scan of up to 1024 block sums, single block of 1024 threads.
__global__ void scanB(int* __restrict__ blockSums, int nb) {
    __shared__ int lds[1024];
    int t = threadIdx.x;
    lds[t] = (t < nb) ? blockSums[t] : 0;
    __syncthreads();
    for (int off = 1; off < 1024; off <<= 1) {
        int v = (t >= off) ? lds[t - off] : 0;
        __syncthreads();
        lds[t] += v;
        __syncthreads();
    }
    if (t < nb) blockSums[t] = (t == 0) ? 0 : lds[t - 1];
}

__global__ void scanC(int* __restrict__ data, const int* __restrict__ blockSums, int n) {
    int idx = blockIdx.x * blockDim.x + threadIdx.x;
    if (idx < n) data[idx] += blockSums[idx >> 10];
    if (idx == 0) data[n] = NE;
}

// Partitioned scatter. blockIdx%8 selects the edge partition so that (under the
// round-robin block->XCD heuristic) each partition's 3.2MB write window stays
// resident in one XCD's L2 and write-combines. Streams use nontemporal loads
// to avoid evicting the write window.
__global__ void scatter_part(const int* __restrict__ src, const int* __restrict__ dst,
                             const float* __restrict__ ew, const float* __restrict__ W,
                             const int* __restrict__ offs,
                             const unsigned short* __restrict__ rank,
                             int2* __restrict__ sorted) {
    int b = blockIdx.x;
    int p = b & 7;
    int j = b >> 3;
    int base = p * CHUNK + j * SCAT_EDGES;
    for (int i = threadIdx.x; i < SCAT_EDGES; i += 256) {
        int e = base + i;
        int d = __builtin_nontemporal_load(dst + e);
        int s = __builtin_nontemporal_load(src + e);
        float w = __builtin_nontemporal_load(ew + e) * W[s];
        int pos = offs[p * NN + d] + (int)__builtin_nontemporal_load(rank + e);
        sorted[pos] = make_int2(s, __float_as_int(w));
    }
}

// ============ per-layer gather (no atomics) ============
// 4 lanes per node; lane q owns classes [4q,4q+4). 8 sub-segments per node
// (one per edge partition); inner loop unrolled x2 for load-latency overlap.
__global__ void gather8(const float* __restrict__ h, const int2* __restrict__ sorted,
                        const int* __restrict__ offs, const float* __restrict__ degree,
                        float* __restrict__ hout) {
    int t = blockIdx.x * blockDim.x + threadIdx.x;
    int g = t >> 2;
    int q = t & 3;
    if (g >= NN) return;
    int q4 = q * 4;
    float4 acc = make_float4(0.f, 0.f, 0.f, 0.f);
#pragma unroll
    for (int p = 0; p < NPART; ++p) {
        int beg = offs[p * NN + g];
        int end = offs[p * NN + g + 1];
        int i = beg;
        for (; i + 2 <= end; i += 2) {
            long long v0 = __builtin_nontemporal_load((const long long*)(sorted + i));
            long long v1 = __builtin_nontemporal_load((const long long*)(sorted + i + 1));
            int s0 = (int)v0; float w0 = __int_as_float((int)(v0 >> 32));
            int s1 = (int)v1; float w1 = __int_as_float((int)(v1 >> 32));
            const float4 h0 = *reinterpret_cast<const float4*>(h + (size_t)s0 * NC + q4);
            const float4 h1 = *reinterpret_cast<const float4*>(h + (size_t)s1 * NC + q4);
            acc.x += h0.x * w0; acc.y += h0.y * w0; acc.z += h0.z * w0; acc.w += h0.w * w0;
            acc.x += h1.x * w1; acc.y += h1.y * w1; acc.z += h1.z * w1; acc.w += h1.w * w1;
        }
        if (i < end) {
            long long v0 = __builtin_nontemporal_load((const long long*)(sorted + i));
            int s0 = (int)v0; float w0 = __int_as_float((int)(v0 >> 32));
            const float4 h0 = *reinterpret_cast<const float4*>(h + (size_t)s0 * NC + q4);
            acc.x += h0.x * w0; acc.y += h0.y * w0; acc.z += h0.z * w0; acc.w += h0.w * w0;
        }
    }
    float deg = degree[g];
    float d2 = deg * deg;
    const float4 hs = *reinterpret_cast<const float4*>(h + (size_t)g * NC + q4);
    float4 v;
    v.x = ALPHA_C * hs.x + (1.f - ALPHA_C) * d2 * acc.x;
    v.y = ALPHA_C * hs.y + (1.f - ALPHA_C) * d2 * acc.y;
    v.z = ALPHA_C * hs.z + (1.f - ALPHA_C) * d2 * acc.z;
    v.w = ALPHA_C * hs.w + (1.f - ALPHA_C) * d2 * acc.w;
    float s4 = v.x + v.y + v.z + v.w;
    s4 += __shfl_xor(s4, 1);
    s4 += __shfl_xor(s4, 2);
    float inv = 1.f / s4;
    v.x *= inv; v.y *= inv; v.z *= inv; v.w *= inv;
    *reinterpret_cast<float4*>(hout + (size_t)g * NC + q4) = v;
}

// ============ fallback path (round-1: single CSR with cursor atomics) ============

__global__ void hist_kernel(const int* __restrict__ dst, int* __restrict__ counts) {
    int e = blockIdx.x * blockDim.x + threadIdx.x;
    if (e < NE) atomicAdd(&counts[dst[e]], 1);
}

__global__ void scatter_sort(const int* __restrict__ src, const int* __restrict__ dst,
                             const float* __restrict__ ew, const float* __restrict__ W,
                             const int* __restrict__ offsets, int* __restrict__ cursor,
                             int2* __restrict__ sorted) {
    int e = blockIdx.x * blockDim.x + threadIdx.x;
    if (e >= NE) return;
    int d = dst[e];
    int s = src[e];
    int pos = offsets[d] + atomicAdd(&cursor[d], 1);
    float w = ew[e] * W[s];
    sorted[pos] = make_int2(s, __float_as_int(w));
}

__global__ void gather_kernel(const float* __restrict__ h,
                              const int2* __restrict__ sorted,
                              const int* __restrict__ offsets,
                              const float* __restrict__ degree,
                              float* __restrict__ hout) {
    int t = blockIdx.x * blockDim.x + threadIdx.x;
    int g = t >> 2;
    int q = t & 3;
    if (g >= NN) return;
    int beg = offsets[g];
    int end = offsets[g + 1];
    float4 acc = make_float4(0.f, 0.f, 0.f, 0.f);
    for (int i = beg; i < end; ++i) {
        int2 rec = sorted[i];
        float w = __int_as_float(rec.y);
        const float4 hv = *reinterpret_cast<const float4*>(h + (size_t)rec.x * NC + q * 4);
        acc.x += hv.x * w; acc.y += hv.y * w; acc.z += hv.z * w; acc.w += hv.w * w;
    }
    float deg = degree[g];
    float d2 = deg * deg;
    const float4 hs = *reinterpret_cast<const float4*>(h + (size_t)g * NC + q * 4);
    float4 v;
    v.x = ALPHA_C * hs.x + (1.f - ALPHA_C) * d2 * acc.x;
    v.y = ALPHA_C * hs.y + (1.f - ALPHA_C) * d2 * acc.y;
    v.z = ALPHA_C * hs.z + (1.f - ALPHA_C) * d2 * acc.z;
    v.w = ALPHA_C * hs.w + (1.f - ALPHA_C) * d2 * acc.w;
    float s4 = v.x + v.y + v.z + v.w;
    s4 += __shfl_xor(s4, 1);
    s4 += __shfl_xor(s4, 2);
    float inv = 1.f / s4;
    float4* op = reinterpret_cast<float4*>(hout + (size_t)g * NC + q * 4);
    v.x *= inv; v.y *= inv; v.z *= inv; v.w *= inv;
    *op = v;
}

// ============ launch ============

extern "C" void kernel_launch(void* const* d_in, const int* in_sizes, int n_in,
                              void* d_out, int out_size, void* d_ws, size_t ws_size,
                              hipStream_t stream)
{
    const float* x      = (const float*)d_in[0];
    const float* W      = (const float*)d_in[1];
    const float* ew     = (const float*)d_in[2];
    const float* degree = (const float*)d_in[3];
    const int*   eidx   = (const int*)d_in[4];
    const int* src = eidx;
    const int* dst = eidx + NE;
    float* out = (float*)d_out;

    const int node_blocks4 = (NN * 4 + 255) / 256;
    const int edge_blocks  = (NE + 255) / 256;

    const size_t sorted_bytes = (size_t)NE * 8;
    const size_t union_bytes  = (size_t)NE * 2 > (size_t)NN * NC * 4
                              ? (size_t)NE * 2 : (size_t)NN * NC * 4;  // rank(u16) vs bufA
    const size_t flat_elems   = (size_t)NPART * NN + 1;
    const size_t need_new = sorted_bytes + union_bytes + flat_elems * 4 + 1024 * 4 + 64;

    if (ws_size >= need_new) {
        int2* sorted = (int2*)d_ws;
        char* upt    = (char*)(sorted + NE);
        unsigned short* rank = (unsigned short*)upt;      // build phase
        float* bufA          = (float*)upt;               // layer phase (rank dead)
        int* flat      = (int*)(upt + union_bytes);
        int* blockSums = flat + flat_elems;

        hipMemsetAsync(flat, 0, flat_elems * sizeof(int), stream);
        hist_rank<<<edge_blocks, 256, 0, stream>>>(dst, flat, rank);

        const int n_scan = NPART * NN;                    // 800000
        const int NB = (n_scan + 1023) / 1024;            // 782
        scanA<<<NB, 256, 0, stream>>>(flat, blockSums, n_scan);
        scanB<<<1, 1024, 0, stream>>>(blockSums, NB);
        scanC<<<(n_scan + 255) / 256, 256, 0, stream>>>(flat, blockSums, n_scan);

        scatter_part<<<NPART * SCAT_J, 256, 0, stream>>>(src, dst, ew, W, flat, rank, sorted);

        const float* hin = x;
        float* houts[NLAYERS] = {bufA, out, bufA, out};
        for (int l = 0; l < NLAYERS; ++l) {
            gather8<<<node_blocks4, 256, 0, stream>>>(hin, sorted, flat, degree, houts[l]);
            hin = houts[l];
        }
        return;
    }

    // -------- round-1 fallback: single CSR --------
    const size_t bufA_elems = (size_t)NN * NC;
    size_t need_r1 = sorted_bytes + bufA_elems * 4 + (size_t)(NN + 1) * 4 + (size_t)NN * 4 + 1024 * 4 + 64;
    if (ws_size >= need_r1) {
        int2*  sorted    = (int2*)d_ws;
        float* bufA      = (float*)(sorted + NE);
        int*   offsets   = (int*)(bufA + bufA_elems);
        int*   cursor    = offsets + (NN + 1);
        int*   blockSums = cursor + NN;

        hipMemsetAsync(offsets, 0, (size_t)(2 * NN + 1) * sizeof(int), stream);
        hist_kernel<<<edge_blocks, 256, 0, stream>>>(dst, offsets);
        const int NB = (NN + 1023) / 1024;
        scanA<<<NB, 256, 0, stream>>>(offsets, blockSums, NN);
        scanB<<<1, 1024, 0, stream>>>(blockSums, NB);
        scanC<<<(NN + 255) / 256, 256, 0, stream>>>(offsets, blockSums, NN);
        scatter_sort<<<edge_blocks, 256, 0, stream>>>(src, dst, ew, W, offsets, cursor, sorted);

        const float* hin = x;
        float* houts[NLAYERS] = {bufA, out, bufA, out};
        for (int l = 0; l < NLAYERS; ++l) {
            gather_kernel<<<node_blocks4, 256, 0, stream>>>(hin, sorted, offsets, degree, houts[l]);
            hin = houts[l];
        }
    }
}

// Round 4
// 314.997 us; speedup vs baseline: 8.1363x; 1.5580x over previous
//
#include <hip/hip_runtime.h>

#define NN 100000
#define NC 16
#define NE 3200000
#define NLAYERS 4
#define ALPHA_C 0.5f

#define BSHIFT 8
#define NBUK 391            // ceil(NN / 256)
#define EPB 4096            // edges per block in bucket passes
#define NBLK 782            // ceil(NE / EPB)
#define CAP 9728            // LDS staging capacity per bucket (mean 8184, +17 sigma)

// ============ build phase (LDS atomics only) ============

// Per-block LDS histogram of coarse buckets (dst>>8).
__global__ void bucket_count(const int* __restrict__ dst, int* __restrict__ counts) {
    __shared__ int h[NBUK];
    for (int i = threadIdx.x; i < NBUK; i += 256) h[i] = 0;
    __syncthreads();
    int base = blockIdx.x * EPB;
    for (int i = threadIdx.x; i < EPB; i += 256) {
        int e = base + i;
        if (e < NE) atomicAdd(&h[dst[e] >> BSHIFT], 1);
    }
    __syncthreads();
    for (int i = threadIdx.x; i < NBUK; i += 256)
        counts[i * NBLK + blockIdx.x] = h[i];   // bucket-major for the scan
}

// Exclusive scan, 1024 elements per block (256 threads x 4 elems).
__global__ void scanA(int* __restrict__ data, int* __restrict__ blockSums, int n) {
    __shared__ int lds[256];
    int base = blockIdx.x * 1024 + threadIdx.x * 4;
    int v[4] = {0, 0, 0, 0};
#pragma unroll
    for (int i = 0; i < 4; ++i) { int idx = base + i; if (idx < n) v[i] = data[idx]; }
    int tsum = v[0] + v[1] + v[2] + v[3];
    lds[threadIdx.x] = tsum;
    __syncthreads();
    for (int off = 1; off < 256; off <<= 1) {
        int t = (threadIdx.x >= off) ? lds[threadIdx.x - off] : 0;
        __syncthreads();
        lds[threadIdx.x] += t;
        __syncthreads();
    }
    if (threadIdx.x == 255) blockSums[blockIdx.x] = lds[255];
    int run = lds[threadIdx.x] - tsum;
#pragma unroll
    for (int i = 0; i < 4; ++i) {
        int idx = base + i;
        if (idx < n) { int old = v[i]; data[idx] = run; run += old; }
    }
}

// Exclusive scan of up to 1024 block sums, single block of 1024 threads.
__global__ void scanB(int* __restrict__ blockSums, int nb) {
    __shared__ int lds[1024];
    int t = threadIdx.x;
    lds[t] = (t < nb) ? blockSums[t] : 0;
    __syncthreads();
    for (int off = 1; off < 1024; off <<= 1) {
        int v = (t >= off) ? lds[t - off] : 0;
        __syncthreads();
        lds[t] += v;
        __syncthreads();
    }
    if (t < nb) blockSums[t] = (t == 0) ? 0 : lds[t - 1];
}

__global__ void scanC(int* __restrict__ data, const int* __restrict__ blockSums, int n) {
    int idx = blockIdx.x * blockDim.x + threadIdx.x;
    if (idx < n) data[idx] += blockSums[idx >> 10];
    if (idx == 0) data[n] = NE;
}

// Re-read edges; LDS-atomic rank within (block,bucket); write 8B records to
// bucket-contiguous positions. rec.x = src | (local_dst << 17), rec.y = w bits.
__global__ void bucket_scatter(const int* __restrict__ src, const int* __restrict__ dst,
                               const float* __restrict__ ew, const float* __restrict__ W,
                               const int* __restrict__ scanned, int2* __restrict__ recs) {
    __shared__ int h[NBUK];
    __shared__ int basep[NBUK];
    for (int i = threadIdx.x; i < NBUK; i += 256) {
        h[i] = 0;
        basep[i] = scanned[i * NBLK + blockIdx.x];
    }
    __syncthreads();
    int base = blockIdx.x * EPB;
    for (int i = threadIdx.x; i < EPB; i += 256) {
        int e = base + i;
        if (e >= NE) continue;
        int d = dst[e];
        int s = src[e];
        float w = ew[e] * W[s];
        int b = d >> BSHIFT;
        int r = atomicAdd(&h[b], 1);
        recs[basep[b] + r] = make_int2(s | ((d & 255) << 17), __float_as_int(w));
    }
}

// One block per bucket: stage records in LDS, counting-sort the 256 local dsts,
// write CSR offsets and rewrite records (src-only) in place, fully dst-sorted.
__global__ void bucket_sort(int2* __restrict__ recs, const int* __restrict__ scanned,
                            int* __restrict__ offsets) {
    __shared__ int2 lrec[CAP];
    __shared__ int hcnt[256];
    __shared__ int hscan[256];
    __shared__ int hexcl[256];
    int b = blockIdx.x;
    int t = threadIdx.x;
    int beg = scanned[b * NBLK];
    int end = (b == NBUK - 1) ? NE : scanned[(b + 1) * NBLK];
    int cnt = end - beg;
    hcnt[t] = 0;
    __syncthreads();
    for (int i = t; i < cnt && i < CAP; i += 256) {
        int2 rv = recs[beg + i];
        lrec[i] = rv;
        atomicAdd(&hcnt[(rv.x >> 17) & 255], 1);
    }
    __syncthreads();
    hscan[t] = hcnt[t];
    __syncthreads();
    for (int off = 1; off < 256; off <<= 1) {
        int v = (t >= off) ? hscan[t - off] : 0;
        __syncthreads();
        hscan[t] += v;
        __syncthreads();
    }
    hexcl[t] = hscan[t] - hcnt[t];
    int d = (b << BSHIFT) + t;
    if (d < NN) offsets[d] = beg + hexcl[t];
    if (b == NBUK - 1 && t == 0) offsets[NN] = NE;
    hcnt[t] = 0;
    __syncthreads();
    for (int i = t; i < cnt && i < CAP; i += 256) {
        int2 rv = lrec[i];
        int ld = (rv.x >> 17) & 255;
        int r = atomicAdd(&hcnt[ld], 1);
        recs[beg + hexcl[ld] + r] = make_int2(rv.x & 0x1FFFF, rv.y);
    }
}

// ============ per-layer gather (single contiguous CSR segment per node) ============
// 4 lanes per node; lane q owns classes [4q,4q+4). Fused deg^2-blend + rownorm.
__global__ void gather1(const float* __restrict__ h, const int2* __restrict__ recs,
                        const int* __restrict__ offsets, const float* __restrict__ degree,
                        float* __restrict__ hout) {
    int t = blockIdx.x * blockDim.x + threadIdx.x;
    int g = t >> 2;
    int q = t & 3;
    if (g >= NN) return;
    int q4 = q * 4;
    int beg = offsets[g];
    int end = offsets[g + 1];
    float4 acc = make_float4(0.f, 0.f, 0.f, 0.f);
    int i = beg;
    for (; i + 2 <= end; i += 2) {
        int2 r0 = recs[i];
        int2 r1 = recs[i + 1];
        float w0 = __int_as_float(r0.y);
        float w1 = __int_as_float(r1.y);
        const float4 h0 = *reinterpret_cast<const float4*>(h + (size_t)r0.x * NC + q4);
        const float4 h1 = *reinterpret_cast<const float4*>(h + (size_t)r1.x * NC + q4);
        acc.x += h0.x * w0; acc.y += h0.y * w0; acc.z += h0.z * w0; acc.w += h0.w * w0;
        acc.x += h1.x * w1; acc.y += h1.y * w1; acc.z += h1.z * w1; acc.w += h1.w * w1;
    }
    if (i < end) {
        int2 r0 = recs[i];
        float w0 = __int_as_float(r0.y);
        const float4 h0 = *reinterpret_cast<const float4*>(h + (size_t)r0.x * NC + q4);
        acc.x += h0.x * w0; acc.y += h0.y * w0; acc.z += h0.z * w0; acc.w += h0.w * w0;
    }
    float deg = degree[g];
    float d2 = deg * deg;
    const float4 hs = *reinterpret_cast<const float4*>(h + (size_t)g * NC + q4);
    float4 v;
    v.x = ALPHA_C * hs.x + (1.f - ALPHA_C) * d2 * acc.x;
    v.y = ALPHA_C * hs.y + (1.f - ALPHA_C) * d2 * acc.y;
    v.z = ALPHA_C * hs.z + (1.f - ALPHA_C) * d2 * acc.z;
    v.w = ALPHA_C * hs.w + (1.f - ALPHA_C) * d2 * acc.w;
    float s4 = v.x + v.y + v.z + v.w;
    s4 += __shfl_xor(s4, 1);
    s4 += __shfl_xor(s4, 2);
    float inv = 1.f / s4;
    v.x *= inv; v.y *= inv; v.z *= inv; v.w *= inv;
    *reinterpret_cast<float4*>(hout + (size_t)g * NC + q4) = v;
}

// ============ fallback (round-1: atomic-cursor CSR) ============

__global__ void hist_kernel(const int* __restrict__ dst, int* __restrict__ counts) {
    int e = blockIdx.x * blockDim.x + threadIdx.x;
    if (e < NE) atomicAdd(&counts[dst[e]], 1);
}

__global__ void scatter_sort(const int* __restrict__ src, const int* __restrict__ dst,
                             const float* __restrict__ ew, const float* __restrict__ W,
                             const int* __restrict__ offsets, int* __restrict__ cursor,
                             int2* __restrict__ sorted) {
    int e = blockIdx.x * blockDim.x + threadIdx.x;
    if (e >= NE) return;
    int d = dst[e];
    int s = src[e];
    int pos = offsets[d] + atomicAdd(&cursor[d], 1);
    float w = ew[e] * W[s];
    sorted[pos] = make_int2(s, __float_as_int(w));
}

// ============ launch ============

extern "C" void kernel_launch(void* const* d_in, const int* in_sizes, int n_in,
                              void* d_out, int out_size, void* d_ws, size_t ws_size,
                              hipStream_t stream)
{
    const float* x      = (const float*)d_in[0];
    const float* W      = (const float*)d_in[1];
    const float* ew     = (const float*)d_in[2];
    const float* degree = (const float*)d_in[3];
    const int*   eidx   = (const int*)d_in[4];
    const int* src = eidx;
    const int* dst = eidx + NE;
    float* out = (float*)d_out;

    const int node_blocks4 = (NN * 4 + 255) / 256;
    const int edge_blocks  = (NE + 255) / 256;

    const size_t recs_elems   = (size_t)NE;            // int2
    const size_t bufA_elems   = (size_t)NN * NC;       // float
    const size_t counts_elems = (size_t)NBUK * NBLK + 1;
    const size_t off_elems    = (size_t)NN + 1;
    const size_t need = recs_elems * 8 + bufA_elems * 4 + counts_elems * 4
                      + off_elems * 4 + 1024 * 4 + 64;

    if (ws_size >= need) {
        int2*  recs      = (int2*)d_ws;
        float* bufA      = (float*)(recs + recs_elems);
        int*   counts    = (int*)(bufA + bufA_elems);
        int*   offsets   = counts + counts_elems;
        int*   blockSums = offsets + off_elems;

        bucket_count<<<NBLK, 256, 0, stream>>>(dst, counts);
        const int n_scan = NBUK * NBLK;                 // 305762
        const int NB = (n_scan + 1023) / 1024;          // 299
        scanA<<<NB, 256, 0, stream>>>(counts, blockSums, n_scan);
        scanB<<<1, 1024, 0, stream>>>(blockSums, NB);
        scanC<<<(n_scan + 255) / 256, 256, 0, stream>>>(counts, blockSums, n_scan);
        bucket_scatter<<<NBLK, 256, 0, stream>>>(src, dst, ew, W, counts, recs);
        bucket_sort<<<NBUK, 256, 0, stream>>>(recs, counts, offsets);

        const float* hin = x;
        float* houts[NLAYERS] = {bufA, out, bufA, out};
        for (int l = 0; l < NLAYERS; ++l) {
            gather1<<<node_blocks4, 256, 0, stream>>>(hin, recs, offsets, degree, houts[l]);
            hin = houts[l];
        }
        return;
    }

    // -------- fallback: single CSR with cursor atomics --------
    {
        int2*  sorted    = (int2*)d_ws;
        float* bufA      = (float*)(sorted + NE);
        int*   offsets   = (int*)(bufA + bufA_elems);
        int*   cursor    = offsets + (NN + 1);
        int*   blockSums = cursor + NN;

        hipMemsetAsync(offsets, 0, (size_t)(2 * NN + 1) * sizeof(int), stream);
        hist_kernel<<<edge_blocks, 256, 0, stream>>>(dst, offsets);
        const int NB = (NN + 1023) / 1024;
        scanA<<<NB, 256, 0, stream>>>(offsets, blockSums, NN);
        scanB<<<1, 1024, 0, stream>>>(blockSums, NB);
        scanC<<<(NN + 255) / 256, 256, 0, stream>>>(offsets, blockSums, NN);
        scatter_sort<<<edge_blocks, 256, 0, stream>>>(src, dst, ew, W, offsets, cursor, sorted);

        const float* hin = x;
        float* houts[NLAYERS] = {bufA, out, bufA, out};
        for (int l = 0; l < NLAYERS; ++l) {
            gather1<<<node_blocks4, 256, 0, stream>>>(hin, sorted, offsets, degree, houts[l]);
            hin = houts[l];
        }
    }
}

// Round 5
// 286.529 us; speedup vs baseline: 8.9447x; 1.0994x over previous
//
#include <hip/hip_runtime.h>

#define NN 100000
#define NC 16
#define NE 3200000
#define NLAYERS 4
#define ALPHA_C 0.5f

#define BSHIFT 8
#define NBUK 391            // ceil(NN / 256)
#define EPB 12288           // edges per block in bucket passes
#define NBLK 261            // ceil(NE / EPB)
#define BKT_THREADS 1024
#define CAP 9728            // LDS staging capacity per bucket (mean 8192, +17 sigma)

// ============ build phase (LDS atomics only) ============

__global__ void bucket_count(const int* __restrict__ dst, int* __restrict__ counts) {
    __shared__ int h[NBUK];
    for (int i = threadIdx.x; i < NBUK; i += BKT_THREADS) h[i] = 0;
    __syncthreads();
    int base = blockIdx.x * EPB;
    for (int i = threadIdx.x; i < EPB; i += BKT_THREADS) {
        int e = base + i;
        if (e < NE) atomicAdd(&h[dst[e] >> BSHIFT], 1);
    }
    __syncthreads();
    for (int i = threadIdx.x; i < NBUK; i += BKT_THREADS)
        counts[i * NBLK + blockIdx.x] = h[i];   // bucket-major for the scan
}

// Exclusive scan, 1024 elements per block (256 threads x 4 elems).
__global__ void scanA(int* __restrict__ data, int* __restrict__ blockSums, int n) {
    __shared__ int lds[256];
    int base = blockIdx.x * 1024 + threadIdx.x * 4;
    int v[4] = {0, 0, 0, 0};
#pragma unroll
    for (int i = 0; i < 4; ++i) { int idx = base + i; if (idx < n) v[i] = data[idx]; }
    int tsum = v[0] + v[1] + v[2] + v[3];
    lds[threadIdx.x] = tsum;
    __syncthreads();
    for (int off = 1; off < 256; off <<= 1) {
        int t = (threadIdx.x >= off) ? lds[threadIdx.x - off] : 0;
        __syncthreads();
        lds[threadIdx.x] += t;
        __syncthreads();
    }
    if (threadIdx.x == 255) blockSums[blockIdx.x] = lds[255];
    int run = lds[threadIdx.x] - tsum;
#pragma unroll
    for (int i = 0; i < 4; ++i) {
        int idx = base + i;
        if (idx < n) { int old = v[i]; data[idx] = run; run += old; }
    }
}

__global__ void scanB(int* __restrict__ blockSums, int nb) {
    __shared__ int lds[1024];
    int t = threadIdx.x;
    lds[t] = (t < nb) ? blockSums[t] : 0;
    __syncthreads();
    for (int off = 1; off < 1024; off <<= 1) {
        int v = (t >= off) ? lds[t - off] : 0;
        __syncthreads();
        lds[t] += v;
        __syncthreads();
    }
    if (t < nb) blockSums[t] = (t == 0) ? 0 : lds[t - 1];
}

__global__ void scanC(int* __restrict__ data, const int* __restrict__ blockSums, int n) {
    int idx = blockIdx.x * blockDim.x + threadIdx.x;
    if (idx < n) data[idx] += blockSums[idx >> 10];
    if (idx == 0) data[n] = NE;
}

// Re-read edges; LDS-atomic rank within (block,bucket); write 8B records to
// bucket-contiguous positions. rec.x = src | (local_dst << 17), rec.y = w bits.
__global__ void bucket_scatter(const int* __restrict__ src, const int* __restrict__ dst,
                               const float* __restrict__ ew, const float* __restrict__ W,
                               const int* __restrict__ scanned, int2* __restrict__ recs) {
    __shared__ int h[NBUK];
    __shared__ int basep[NBUK];
    for (int i = threadIdx.x; i < NBUK; i += BKT_THREADS) {
        h[i] = 0;
        basep[i] = scanned[i * NBLK + blockIdx.x];
    }
    __syncthreads();
    int base = blockIdx.x * EPB;
    for (int i = threadIdx.x; i < EPB; i += BKT_THREADS) {
        int e = base + i;
        if (e >= NE) continue;
        int d = dst[e];
        int s = src[e];
        float w = ew[e] * W[s];
        int b = d >> BSHIFT;
        int r = atomicAdd(&h[b], 1);
        recs[basep[b] + r] = make_int2(s | ((d & 255) << 17), __float_as_int(w));
    }
}

// One block (512 thr) per bucket: stage records in LDS, counting-sort the 256
// local dsts, write CSR offsets, rewrite records in place fully dst-sorted.
__global__ void bucket_sort(int2* __restrict__ recs, const int* __restrict__ scanned,
                            int* __restrict__ offsets) {
    __shared__ int2 lrec[CAP];
    __shared__ int hcnt[256];
    __shared__ int hscan[256];
    __shared__ int hexcl[256];
    int b = blockIdx.x;
    int t = threadIdx.x;
    int beg = scanned[b * NBLK];
    int end = (b == NBUK - 1) ? NE : scanned[(b + 1) * NBLK];
    int cnt = end - beg;
    if (t < 256) hcnt[t] = 0;
    __syncthreads();
    for (int i = t; i < cnt && i < CAP; i += 512) {
        int2 rv = recs[beg + i];
        lrec[i] = rv;
        atomicAdd(&hcnt[(rv.x >> 17) & 255], 1);
    }
    __syncthreads();
    if (t < 256) hscan[t] = hcnt[t];
    __syncthreads();
    for (int off = 1; off < 256; off <<= 1) {
        int v = 0;
        if (t >= off && t < 256) v = hscan[t - off];
        __syncthreads();
        if (t < 256) hscan[t] += v;
        __syncthreads();
    }
    if (t < 256) {
        hexcl[t] = hscan[t] - hcnt[t];
        int d = (b << BSHIFT) + t;
        if (d < NN) offsets[d] = beg + hexcl[t];
        hcnt[t] = 0;
    }
    if (b == NBUK - 1 && t == 0) offsets[NN] = NE;
    __syncthreads();
    for (int i = t; i < cnt && i < CAP; i += 512) {
        int2 rv = lrec[i];
        int ld = (rv.x >> 17) & 255;
        int r = atomicAdd(&hcnt[ld], 1);
        recs[beg + hexcl[ld] + r] = make_int2(rv.x & 0x1FFFF, rv.y);
    }
}

// ============ per-layer gather (contiguous CSR segment per node) ============
// 4 lanes per node; lane q owns classes [4q,4q+4). Fused deg^2-blend + rownorm.
__global__ void gather1(const float* __restrict__ h, const int2* __restrict__ recs,
                        const int* __restrict__ offsets, const float* __restrict__ degree,
                        float* __restrict__ hout) {
    int t = blockIdx.x * blockDim.x + threadIdx.x;
    int g = t >> 2;
    int q = t & 3;
    if (g >= NN) return;
    int q4 = q * 4;
    int beg = offsets[g];
    int end = offsets[g + 1];
    float4 acc = make_float4(0.f, 0.f, 0.f, 0.f);
    int i = beg;
    for (; i + 4 <= end; i += 4) {
        int2 r0 = recs[i];
        int2 r1 = recs[i + 1];
        int2 r2 = recs[i + 2];
        int2 r3 = recs[i + 3];
        const float4 h0 = *reinterpret_cast<const float4*>(h + (size_t)r0.x * NC + q4);
        const float4 h1 = *reinterpret_cast<const float4*>(h + (size_t)r1.x * NC + q4);
        const float4 h2 = *reinterpret_cast<const float4*>(h + (size_t)r2.x * NC + q4);
        const float4 h3 = *reinterpret_cast<const float4*>(h + (size_t)r3.x * NC + q4);
        float w0 = __int_as_float(r0.y), w1 = __int_as_float(r1.y);
        float w2 = __int_as_float(r2.y), w3 = __int_as_float(r3.y);
        acc.x += h0.x * w0; acc.y += h0.y * w0; acc.z += h0.z * w0; acc.w += h0.w * w0;
        acc.x += h1.x * w1; acc.y += h1.y * w1; acc.z += h1.z * w1; acc.w += h1.w * w1;
        acc.x += h2.x * w2; acc.y += h2.y * w2; acc.z += h2.z * w2; acc.w += h2.w * w2;
        acc.x += h3.x * w3; acc.y += h3.y * w3; acc.z += h3.z * w3; acc.w += h3.w * w3;
    }
    for (; i < end; ++i) {
        int2 r0 = recs[i];
        float w0 = __int_as_float(r0.y);
        const float4 h0 = *reinterpret_cast<const float4*>(h + (size_t)r0.x * NC + q4);
        acc.x += h0.x * w0; acc.y += h0.y * w0; acc.z += h0.z * w0; acc.w += h0.w * w0;
    }
    float deg = degree[g];
    float d2 = deg * deg;
    const float4 hs = *reinterpret_cast<const float4*>(h + (size_t)g * NC + q4);
    float4 v;
    v.x = ALPHA_C * hs.x + (1.f - ALPHA_C) * d2 * acc.x;
    v.y = ALPHA_C * hs.y + (1.f - ALPHA_C) * d2 * acc.y;
    v.z = ALPHA_C * hs.z + (1.f - ALPHA_C) * d2 * acc.z;
    v.w = ALPHA_C * hs.w + (1.f - ALPHA_C) * d2 * acc.w;
    float s4 = v.x + v.y + v.z + v.w;
    s4 += __shfl_xor(s4, 1);
    s4 += __shfl_xor(s4, 2);
    float inv = 1.f / s4;
    v.x *= inv; v.y *= inv; v.z *= inv; v.w *= inv;
    *reinterpret_cast<float4*>(hout + (size_t)g * NC + q4) = v;
}

// ============ fallback (atomic-cursor CSR) ============

__global__ void hist_kernel(const int* __restrict__ dst, int* __restrict__ counts) {
    int e = blockIdx.x * blockDim.x + threadIdx.x;
    if (e < NE) atomicAdd(&counts[dst[e]], 1);
}

__global__ void scatter_sort(const int* __restrict__ src, const int* __restrict__ dst,
                             const float* __restrict__ ew, const float* __restrict__ W,
                             const int* __restrict__ offsets, int* __restrict__ cursor,
                             int2* __restrict__ sorted) {
    int e = blockIdx.x * blockDim.x + threadIdx.x;
    if (e >= NE) return;
    int d = dst[e];
    int s = src[e];
    int pos = offsets[d] + atomicAdd(&cursor[d], 1);
    float w = ew[e] * W[s];
    sorted[pos] = make_int2(s, __float_as_int(w));
}

// ============ launch ============

extern "C" void kernel_launch(void* const* d_in, const int* in_sizes, int n_in,
                              void* d_out, int out_size, void* d_ws, size_t ws_size,
                              hipStream_t stream)
{
    const float* x      = (const float*)d_in[0];
    const float* W      = (const float*)d_in[1];
    const float* ew     = (const float*)d_in[2];
    const float* degree = (const float*)d_in[3];
    const int*   eidx   = (const int*)d_in[4];
    const int* src = eidx;
    const int* dst = eidx + NE;
    float* out = (float*)d_out;

    const int node_blocks4 = (NN * 4 + 255) / 256;
    const int edge_blocks  = (NE + 255) / 256;

    const size_t recs_elems   = (size_t)NE;            // int2
    const size_t bufA_elems   = (size_t)NN * NC;       // float
    const size_t counts_elems = (size_t)NBUK * NBLK + 1;
    const size_t off_elems    = (size_t)NN + 1;
    const size_t need = recs_elems * 8 + bufA_elems * 4 + counts_elems * 4
                      + off_elems * 4 + 1024 * 4 + 64;

    if (ws_size >= need) {
        int2*  recs      = (int2*)d_ws;
        float* bufA      = (float*)(recs + recs_elems);
        int*   counts    = (int*)(bufA + bufA_elems);
        int*   offsets   = counts + counts_elems;
        int*   blockSums = offsets + off_elems;

        bucket_count<<<NBLK, BKT_THREADS, 0, stream>>>(dst, counts);
        const int n_scan = NBUK * NBLK;                 // 102051
        const int NB = (n_scan + 1023) / 1024;          // 100
        scanA<<<NB, 256, 0, stream>>>(counts, blockSums, n_scan);
        scanB<<<1, 1024, 0, stream>>>(blockSums, NB);
        scanC<<<(n_scan + 255) / 256, 256, 0, stream>>>(counts, blockSums, n_scan);
        bucket_scatter<<<NBLK, BKT_THREADS, 0, stream>>>(src, dst, ew, W, counts, recs);
        bucket_sort<<<NBUK, 512, 0, stream>>>(recs, counts, offsets);

        const float* hin = x;
        float* houts[NLAYERS] = {bufA, out, bufA, out};
        for (int l = 0; l < NLAYERS; ++l) {
            gather1<<<node_blocks4, 256, 0, stream>>>(hin, recs, offsets, degree, houts[l]);
            hin = houts[l];
        }
        return;
    }

    // -------- fallback: single CSR with cursor atomics --------
    {
        int2*  sorted    = (int2*)d_ws;
        float* bufA      = (float*)(sorted + NE);
        int*   offsets   = (int*)(bufA + bufA_elems);
        int*   cursor    = offsets + (NN + 1);
        int*   blockSums = cursor + NN;

        hipMemsetAsync(offsets, 0, (size_t)(2 * NN + 1) * sizeof(int), stream);
        hist_kernel<<<edge_blocks, 256, 0, stream>>>(dst, offsets);
        const int NB = (NN + 1023) / 1024;
        scanA<<<NB, 256, 0, stream>>>(offsets, blockSums, NN);
        scanB<<<1, 1024, 0, stream>>>(blockSums, NB);
        scanC<<<(NN + 255) / 256, 256, 0, stream>>>(offsets, blockSums, NN);
        scatter_sort<<<edge_blocks, 256, 0, stream>>>(src, dst, ew, W, offsets, cursor, sorted);

        const float* hin = x;
        float* houts[NLAYERS] = {bufA, out, bufA, out};
        for (int l = 0; l < NLAYERS; ++l) {
            gather1<<<node_blocks4, 256, 0, stream>>>(hin, sorted, offsets, degree, houts[l]);
            hin = houts[l];
        }
    }
}